// Round 6
// baseline (209.107 us; speedup 1.0000x reference)
//
#include <hip/hip_runtime.h>

#define S_DIM 128
#define N_DIM 256
#define CIN   256
#define CH    32
#define COUT  128

typedef __attribute__((ext_vector_type(8))) short bf16x8;
typedef __attribute__((ext_vector_type(4))) float f32x4;

__device__ __forceinline__ unsigned short f2bf(float f) {
  union { float f; unsigned int u; } v; v.f = f;
  unsigned int u = v.u;
  return (unsigned short)((u + 0x7FFFu + ((u >> 16) & 1u)) >> 16);
}

// ---------------------------------------------------------------------------
// K0: merged streaming LN + prep. Zero LDS -> max occupancy.
// ---------------------------------------------------------------------------
__global__ __launch_bounds__(256) void k0_ln_prep(
    const float* __restrict__ m, const float* __restrict__ mask,
    const float* __restrict__ gamma, const float* __restrict__ beta,
    const float* __restrict__ Wa, const float* __restrict__ Wb,
    const float* __restrict__ Wo,
    float* __restrict__ rnm, unsigned short* __restrict__ wab_bf,
    unsigned short* __restrict__ wo2, unsigned short* __restrict__ mn_g) {
  const int b = blockIdx.x, t = threadIdx.x;
  if (b < 2048) {
    const int w = t >> 6, l = t & 63;
    const int rbase = b * 16 + w * 4;          // rows rid = s*256 + i
    const float4 g4 = *(const float4*)(gamma + l * 4);
    const float4 b4 = *(const float4*)(beta + l * 4);
    float4 v[4];
    #pragma unroll
    for (int rr = 0; rr < 4; rr++)
      v[rr] = *(const float4*)(m + (size_t)(rbase + rr) * CIN + l * 4);
    #pragma unroll
    for (int rr = 0; rr < 4; rr++) {
      float sum = v[rr].x + v[rr].y + v[rr].z + v[rr].w;
      float sq  = v[rr].x * v[rr].x + v[rr].y * v[rr].y +
                  v[rr].z * v[rr].z + v[rr].w * v[rr].w;
      #pragma unroll
      for (int off = 32; off > 0; off >>= 1) {
        sum += __shfl_down(sum, off);
        sq  += __shfl_down(sq, off);
      }
      sum = __shfl(sum, 0); sq = __shfl(sq, 0);
      const float mu = sum * (1.0f / CIN);
      const float var = fmaxf(sq * (1.0f / CIN) - mu * mu, 0.0f);
      const float rs = rsqrtf(var + 1e-5f);
      const float mk = mask[rbase + rr];
      ushort4 p;
      p.x = f2bf(((v[rr].x - mu) * rs * g4.x + b4.x) * mk);
      p.y = f2bf(((v[rr].y - mu) * rs * g4.y + b4.y) * mk);
      p.z = f2bf(((v[rr].z - mu) * rs * g4.z + b4.z) * mk);
      p.w = f2bf(((v[rr].w - mu) * rs * g4.w + b4.w) * mk);
      *(ushort4*)(mn_g + (size_t)(rbase + rr) * CIN + l * 4) = p;
    }
  } else if (b < 2112) {
    const int r = b - 2048;  // 0..63
    const float* src = (r < 32) ? (Wa + r * CIN) : (Wb + (r - 32) * CIN);
    wab_bf[r * CIN + t] = f2bf(src[t]);
  } else if (b < 2240) {
    // wo2[((ot*32+kk)*64 + lane)*8 + e] = Wo[o=ot*16+(lane&15)][c*32+d],
    // storage k' = kk*32 + (lane>>4)*8 + e; c = k'&31, d = k'>>5
    const int r = b - 2112;  // 0..127
    #pragma unroll
    for (int q = 0; q < 4; q++) {
      const int f = r * 1024 + q * 256 + t;
      const int e = f & 7, l = (f >> 3) & 63, kk = (f >> 9) & 31, ot = f >> 14;
      const int kp = kk * 32 + (l >> 4) * 8 + e;
      const int c = kp & 31, d = kp >> 5;
      const int o = ot * 16 + (l & 15);
      wo2[f] = f2bf(Wo[o * 1024 + c * 32 + d]);
    }
  } else {
    const int i = b - 2240;  // 0..255
    float acc = 0.f;
    #pragma unroll 8
    for (int s = 0; s < S_DIM; s++)
      acc += mask[s * N_DIM + i] * mask[s * N_DIM + t];
    acc = fmaxf(acc, 1.0f);
    rnm[i * N_DIM + t] = 1.0f / acc;
  }
}

// ---------------------------------------------------------------------------
// K_proj: mn_g (bf16) -> a_t/b_t via MFMA.  Block = (i, 32-s group).
// a_t[(i*32+c)][s], b_t likewise (8192 x 128 bf16 each).
// ---------------------------------------------------------------------------
__global__ __launch_bounds__(256) void proj_kernel(
    const unsigned short* __restrict__ mn_g,
    const unsigned short* __restrict__ wab_bf,
    unsigned short* __restrict__ a_t, unsigned short* __restrict__ b_t) {
  __shared__ __align__(16) unsigned short mn[32][264];  // +8 pad
  const int i = blockIdx.x;
  const int s0 = blockIdx.y * 32;
  const int t = threadIdx.x, w = t >> 6, l = t & 63;
  const int lq = l >> 4, lr = l & 15;

  #pragma unroll
  for (int rr = 0; rr < 8; rr++) {
    const int r = w * 8 + rr;
    const size_t rid = (size_t)(s0 + r) * N_DIM + i;
    *(ushort4*)(&mn[r][l * 4]) = *(const ushort4*)(mn_g + rid * CIN + l * 4);
  }
  __syncthreads();

  const int wm = w & 1;   // s-half
  const int n2 = w >> 1;  // 0 -> a, 1 -> b
  f32x4 acc0 = {0.f, 0.f, 0.f, 0.f}, acc1 = {0.f, 0.f, 0.f, 0.f};
  #pragma unroll
  for (int ks = 0; ks < 8; ks++) {
    const int k0 = ks * 32 + lq * 8;
    const bf16x8 af = *(const bf16x8*)(&mn[wm * 16 + lr][k0]);
    const unsigned short* wrow = wab_bf + (n2 * 32 + lr) * CIN + k0;
    const bf16x8 bf0 = *(const bf16x8*)(wrow);
    const bf16x8 bf1 = *(const bf16x8*)(wrow + 16 * CIN);
    acc0 = __builtin_amdgcn_mfma_f32_16x16x32_bf16(af, bf0, acc0, 0, 0, 0);
    acc1 = __builtin_amdgcn_mfma_f32_16x16x32_bf16(af, bf1, acc1, 0, 0, 0);
  }

  unsigned short* dst = (n2 == 0) ? a_t : b_t;
  const int scol = s0 + wm * 16 + lq * 4;
  ushort4 q0, q1;
  q0.x = f2bf(acc0[0]); q0.y = f2bf(acc0[1]); q0.z = f2bf(acc0[2]); q0.w = f2bf(acc0[3]);
  q1.x = f2bf(acc1[0]); q1.y = f2bf(acc1[1]); q1.z = f2bf(acc1[2]); q1.w = f2bf(acc1[3]);
  *(ushort4*)(dst + ((size_t)(i * CH + lr)) * S_DIM + scol) = q0;
  *(ushort4*)(dst + ((size_t)(i * CH + 16 + lr)) * S_DIM + scol) = q1;
}

// ---------------------------------------------------------------------------
// fused v3: 256x256 z-tile (64 pairs), 16 waves, 128 KB dynamic LDS (sZ only).
//   GEMM1  : A/B fragments read DIRECTLY from L2 (a_t/b_t hot, aligned b128) —
//            no staging, no stage barrier.
//   transp : each wave owns 4 whole 32x32 pair-blocks -> disjoint sZ writes,
//            no barrier needed before them. ONE barrier total (before GEMM2).
//   GEMM2  : wave = (pair-group pg = w&3 [16 pairs], o-group og = w>>2 [32 o])
//            -> each z fragment read once per 2 o-tiles (fanout-2), Wo frags
//            L1-reused by the 4 pair-group waves.
// ---------------------------------------------------------------------------
__global__ __launch_bounds__(1024, 4) void fused_kernel(
    const unsigned short* __restrict__ a_t, const unsigned short* __restrict__ b_t,
    const unsigned short* __restrict__ wo2, const float* __restrict__ rnm,
    const float* __restrict__ bo, float* __restrict__ out) {
  extern __shared__ __align__(16) unsigned short sZ[];   // 64 pairs x 1024

  const int t = threadIdx.x, w = t >> 6, l = t & 63;
  const int lq = l >> 4, lr = l & 15;
  const int bx = blockIdx.x, by = blockIdx.y;

  // GEMM1: K=128 = 4 MFMA k-steps; wave (wy,wx) owns 64x64 of 256x256.
  // Fragments straight from global (L2): row-contiguous b128 loads.
  const int wy = (w >> 2) * 64, wx = (w & 3) * 64;
  const unsigned short* srcA = a_t + (size_t)bx * 32768;   // 256 rows x 128
  const unsigned short* srcB = b_t + (size_t)by * 32768;
  f32x4 acc[4][4];
  #pragma unroll
  for (int a = 0; a < 4; a++)
    #pragma unroll
    for (int c = 0; c < 4; c++) acc[a][c] = (f32x4){0.f, 0.f, 0.f, 0.f};

  #pragma unroll
  for (int ks = 0; ks < 4; ks++) {
    const int kcol = ks * 32 + lq * 8;
    bf16x8 afr[4], bfr[4];
    #pragma unroll
    for (int a = 0; a < 4; a++) {
      afr[a] = *(const bf16x8*)(srcA + (wy + a * 16 + lr) * 128 + kcol);
      bfr[a] = *(const bf16x8*)(srcB + (wx + a * 16 + lr) * 128 + kcol);
    }
    #pragma unroll
    for (int a = 0; a < 4; a++)
      #pragma unroll
      for (int c = 0; c < 4; c++)
        acc[a][c] = __builtin_amdgcn_mfma_f32_16x16x32_bf16(afr[a], bfr[c], acc[a][c], 0, 0, 0);
  }

  // Transpose: acc (C/D layout) -> sZ[pair][k'=d*32+c], b64 writes.
  // Wave's 4 pair-blocks are exclusive -> no barrier before this.
  // Granule map: gp = (g&~7) | ((g ^ (g>>3) ^ pair) & 7)
  #pragma unroll
  for (int a = 0; a < 4; a++) {
    #pragma unroll
    for (int c = 0; c < 4; c++) {
      const int zrb = wy + a * 16 + lq * 4;          // c-coord base (+0..3 regs)
      const int zc  = wx + c * 16 + lr;              // d-coord
      const int pair = (zrb >> 5) * 8 + (zc >> 5);   // 0..63
      const int off = (zc & 31) * 32 + (zrb & 31);   // k' = d*32 + c
      const int g = off >> 3;
      const int gp = (g & ~7) | ((g ^ (g >> 3) ^ pair) & 7);
      ushort4 q;
      q.x = f2bf(acc[a][c][0]); q.y = f2bf(acc[a][c][1]);
      q.z = f2bf(acc[a][c][2]); q.w = f2bf(acc[a][c][3]);
      *(ushort4*)(&sZ[pair * 1024 + gp * 8 + (off & 7)]) = q;
    }
  }
  __syncthreads();   // the ONE barrier: all z written before GEMM2 reads

  // GEMM2: wave = (pg = w&3, og = w>>2). 16 pairs x 32 o x K=1024.
  const int pg = w & 3, og = w >> 2;
  const int p = pg * 16 + lr;
  const unsigned short* wbase0 = wo2 + (size_t)(og * 2) * 16384 + (size_t)l * 8;
  const unsigned short* wbase1 = wbase0 + 16384;
  f32x4 oa[2][2];
  oa[0][0] = oa[0][1] = oa[1][0] = oa[1][1] = (f32x4){0.f, 0.f, 0.f, 0.f};
  #pragma unroll 4
  for (int kk = 0; kk < 32; kk++) {
    const int g = kk * 4 + lq;
    const int gp = (g & ~7) | ((g ^ (g >> 3) ^ p) & 7);
    const bf16x8 zf = *(const bf16x8*)(&sZ[p * 1024 + gp * 8]);
    const bf16x8 w0 = *(const bf16x8*)(wbase0 + kk * 512);
    const bf16x8 w1 = *(const bf16x8*)(wbase1 + kk * 512);
    oa[0][kk & 1] = __builtin_amdgcn_mfma_f32_16x16x32_bf16(zf, w0, oa[0][kk & 1], 0, 0, 0);
    oa[1][kk & 1] = __builtin_amdgcn_mfma_f32_16x16x32_bf16(zf, w1, oa[1][kk & 1], 0, 0, 0);
  }

  // Epilogue: D col = o (lr), row = pair-in-group (lq*4+r)
  #pragma unroll
  for (int f = 0; f < 2; f++) {
    const int o = (og * 2 + f) * 16 + lr;
    const float bov = bo[o];
    #pragma unroll
    for (int r = 0; r < 4; r++) {
      const int pair = pg * 16 + lq * 4 + r;
      const int ii = bx * 8 + (pair >> 3);
      const int jj = by * 8 + (pair & 7);
      const float sc = rnm[ii * N_DIM + jj];
      out[((size_t)(ii * N_DIM + jj)) * COUT + o] =
          (oa[f][0][r] + oa[f][1][r]) * sc + bov;
    }
  }
}

// ---------------------------------------------------------------------------
extern "C" void kernel_launch(void* const* d_in, const int* in_sizes, int n_in,
                              void* d_out, int out_size, void* d_ws, size_t ws_size,
                              hipStream_t stream) {
  const float* m     = (const float*)d_in[0];
  const float* mask  = (const float*)d_in[1];
  const float* gamma = (const float*)d_in[2];
  const float* beta  = (const float*)d_in[3];
  const float* Wa    = (const float*)d_in[4];
  const float* Wb    = (const float*)d_in[5];
  const float* Wo    = (const float*)d_in[6];
  const float* bo    = (const float*)d_in[7];
  float* out = (float*)d_out;

  char* ws = (char*)d_ws;
  float*          rnm    = (float*)(ws);                     // 256 KB
  unsigned short* wo2    = (unsigned short*)(ws + 262144);   // 256 KB
  unsigned short* wab_bf = (unsigned short*)(ws + 524288);   //  32 KB
  unsigned short* a_t    = (unsigned short*)(ws + 557056);   //   2 MB
  unsigned short* b_t    = (unsigned short*)(ws + 2654208);  //   2 MB
  unsigned short* mn_g   = (unsigned short*)(ws + 4751360);  // 16.8 MB

  hipFuncSetAttribute((const void*)fused_kernel,
                      hipFuncAttributeMaxDynamicSharedMemorySize, 131072);

  k0_ln_prep<<<2496, 256, 0, stream>>>(m, mask, gamma, beta, Wa, Wb, Wo,
                                       rnm, wab_bf, wo2, mn_g);
  proj_kernel<<<dim3(256, 4), 256, 0, stream>>>(mn_g, wab_bf, a_t, b_t);
  fused_kernel<<<dim3(32, 32), 1024, 131072, stream>>>(a_t, b_t, wo2, rnm, bo, out);
}

// Round 7
// 157.214 us; speedup vs baseline: 1.3301x; 1.3301x over previous
//
#include <hip/hip_runtime.h>
#include <hip/hip_bf16.h>

#define S_DIM 128
#define N_DIM 256
#define CIN   256
#define CH    32
#define COUT  128

typedef __attribute__((ext_vector_type(8))) short bf16x8;
typedef __attribute__((ext_vector_type(4))) float f32x4;

__device__ __forceinline__ unsigned short f2bf(float f) {
  union { float f; unsigned int u; } v; v.f = f;
  unsigned int u = v.u;
  return (unsigned short)((u + 0x7FFFu + ((u >> 16) & 1u)) >> 16);
}

// packed f32x2 -> bf16x2 (RNE), single v_cvt_pk_bf16_f32
__device__ __forceinline__ unsigned int pk2(float x, float y) {
  float2 f2; f2.x = x; f2.y = y;
  __hip_bfloat162 h = __float22bfloat162_rn(f2);
  union { __hip_bfloat162 h; unsigned int u; } c; c.h = h;
  return c.u;
}

// ---------------------------------------------------------------------------
// Front-end (R4-verified): merged LN+projection and prep.
//   blocks 0..1023   : LayerNorm + MFMA projection (wab in LDS)
//   blocks 1024..1151: wo2 = Wo bf16 permuted to [ot][kk][lane][8], k'=d*32+c
//   blocks 1152..1407: rnm = 1 / clip(mask^T mask, 1)
// ---------------------------------------------------------------------------
__global__ __launch_bounds__(256) void lnp_prep_kernel(
    const float* __restrict__ m, const float* __restrict__ mask,
    const float* __restrict__ gamma, const float* __restrict__ beta,
    const float* __restrict__ Wa, const float* __restrict__ Wb,
    const float* __restrict__ Wo,
    float* __restrict__ rnm, unsigned short* __restrict__ wo2,
    unsigned short* __restrict__ a_t, unsigned short* __restrict__ b_t) {
  const int b = blockIdx.x, t = threadIdx.x;
  if (b < 1024) {
    __shared__ __align__(16) unsigned short mn[32][264];   // +8 pad
    __shared__ __align__(16) unsigned short wabs[64 * 256];
    const int i = b & 255, s0 = (b >> 8) * 32;
    const int w = t >> 6, l = t & 63, lq = l >> 4, lr = l & 15;

    // Wa/Wb -> wabs, granule-swizzled: g' = (g&16)|((g ^ (r&15))&15)
    #pragma unroll
    for (int it = 0; it < 8; it++) {
      const int gi = it * 256 + t;       // granule 0..2047 (64 rows x 32)
      const int r = gi >> 5, g = gi & 31;
      const float* src = (r < 32) ? (Wa + r * 256 + g * 8)
                                  : (Wb + (r - 32) * 256 + g * 8);
      const int gp = (g & 16) | ((g ^ (r & 15)) & 15);
      unsigned short* dst = &wabs[r * 256 + gp * 8];
      const float4 v0 = *(const float4*)(src);
      const float4 v1 = *(const float4*)(src + 4);
      dst[0] = f2bf(v0.x); dst[1] = f2bf(v0.y); dst[2] = f2bf(v0.z); dst[3] = f2bf(v0.w);
      dst[4] = f2bf(v1.x); dst[5] = f2bf(v1.y); dst[6] = f2bf(v1.z); dst[7] = f2bf(v1.w);
    }

    const float4 g4 = *(const float4*)(gamma + l * 4);
    const float4 b4 = *(const float4*)(beta + l * 4);

    for (int rr = 0; rr < 8; rr++) {
      const int r = w * 8 + rr;
      const int s = s0 + r;
      const float4 v = *(const float4*)(m + ((size_t)(s * N_DIM + i)) * CIN + l * 4);
      float sum = v.x + v.y + v.z + v.w;
      float sq  = v.x * v.x + v.y * v.y + v.z * v.z + v.w * v.w;
      #pragma unroll
      for (int off = 32; off > 0; off >>= 1) {
        sum += __shfl_down(sum, off);
        sq  += __shfl_down(sq, off);
      }
      sum = __shfl(sum, 0); sq = __shfl(sq, 0);
      const float mu = sum * (1.0f / CIN);
      const float var = fmaxf(sq * (1.0f / CIN) - mu * mu, 0.0f);
      const float rs = rsqrtf(var + 1e-5f);
      const float mk = mask[s * N_DIM + i];
      ushort4 p;
      p.x = f2bf(((v.x - mu) * rs * g4.x + b4.x) * mk);
      p.y = f2bf(((v.y - mu) * rs * g4.y + b4.y) * mk);
      p.z = f2bf(((v.z - mu) * rs * g4.z + b4.z) * mk);
      p.w = f2bf(((v.w - mu) * rs * g4.w + b4.w) * mk);
      *(ushort4*)(&mn[r][l * 4]) = p;
    }
    __syncthreads();

    // MFMA: M=32 s-rows, N=64 [Wa|Wb], K=256
    const int wm = w & 1;
    const int n2 = w >> 1;
    f32x4 acc0 = {0.f, 0.f, 0.f, 0.f}, acc1 = {0.f, 0.f, 0.f, 0.f};
    #pragma unroll
    for (int ks = 0; ks < 8; ks++) {
      const int k0 = ks * 32 + lq * 8;
      const int g = ks * 4 + lq;
      const int gp = (g & 16) | ((g ^ lr) & 15);
      const bf16x8 af = *(const bf16x8*)(&mn[wm * 16 + lr][k0]);
      const bf16x8 bf0 = *(const bf16x8*)(&wabs[(n2 * 32 + lr) * 256 + gp * 8]);
      const bf16x8 bf1 = *(const bf16x8*)(&wabs[(n2 * 32 + 16 + lr) * 256 + gp * 8]);
      acc0 = __builtin_amdgcn_mfma_f32_16x16x32_bf16(af, bf0, acc0, 0, 0, 0);
      acc1 = __builtin_amdgcn_mfma_f32_16x16x32_bf16(af, bf1, acc1, 0, 0, 0);
    }

    unsigned short* dst = (n2 == 0) ? a_t : b_t;
    const int scol = s0 + wm * 16 + lq * 4;
    ushort4 q0, q1;
    q0.x = f2bf(acc0[0]); q0.y = f2bf(acc0[1]); q0.z = f2bf(acc0[2]); q0.w = f2bf(acc0[3]);
    q1.x = f2bf(acc1[0]); q1.y = f2bf(acc1[1]); q1.z = f2bf(acc1[2]); q1.w = f2bf(acc1[3]);
    *(ushort4*)(dst + ((size_t)(i * CH + lr)) * S_DIM + scol) = q0;
    *(ushort4*)(dst + ((size_t)(i * CH + 16 + lr)) * S_DIM + scol) = q1;
  } else if (b < 1152) {
    // wo2[((ot*32+kk)*64 + lane)*8 + e] = Wo[o=ot*16+(lane&15)][c*32+d]
    const int r = b - 1024;  // 0..127
    #pragma unroll
    for (int q = 0; q < 4; q++) {
      const int f = r * 1024 + q * 256 + t;
      const int e = f & 7, l = (f >> 3) & 63, kk = (f >> 9) & 31, ot = f >> 14;
      const int kp = kk * 32 + (l >> 4) * 8 + e;
      const int c = kp & 31, d = kp >> 5;
      const int o = ot * 16 + (l & 15);
      wo2[f] = f2bf(Wo[o * 1024 + c * 32 + d]);
    }
  } else {
    const int i = b - 1152;  // 0..255
    float acc = 0.f;
    #pragma unroll 8
    for (int s = 0; s < S_DIM; s++)
      acc += mask[s * N_DIM + i] * mask[s * N_DIM + t];
    acc = fmaxf(acc, 1.0f);
    rnm[i * N_DIM + t] = 1.0f / acc;
  }
}

// ---------------------------------------------------------------------------
// fused v4 = R5's staged GEMM1 (verified) + R6's fanout-2 GEMM2 (verified).
// 256x256 z-tile (64 pairs), 16 waves, 128 KB dynamic LDS, grid 32x32.
//   stage  : sA/sB 64 KB each, XOR-swizzled 16B granules  (LDS as latency
//            absorber — R6 proved direct-L2 MFMA streaming is 2x worse)
//   GEMM1  : wave grid 4x4, 64x64 per wave, K=128
//   transp : C/D accs -> sZ[pair][k'=d*32+c] (b64, packed cvt; overlays sA/sB)
//   GEMM2  : wave = (pg = w&3: 16 pairs, og = w>>2: 32 o) -> z read ONCE/kk
// ---------------------------------------------------------------------------
__global__ __launch_bounds__(1024, 4) void fused_kernel(
    const unsigned short* __restrict__ a_t, const unsigned short* __restrict__ b_t,
    const unsigned short* __restrict__ wo2, const float* __restrict__ rnm,
    const float* __restrict__ bo, float* __restrict__ out) {
  extern __shared__ __align__(16) unsigned short smem[];
  unsigned short* sA = smem;            // 256 x 128 = 64 KB
  unsigned short* sB = smem + 32768;    // 256 x 128 = 64 KB
  unsigned short* sZ = smem;            // 64 pairs x 1024 = 128 KB overlay

  const int t = threadIdx.x, w = t >> 6, l = t & 63;
  const int lq = l >> 4, lr = l & 15;
  const int bx = blockIdx.x, by = blockIdx.y;

  // Stage: 4096 granules/tile; swizzle g' = g ^ (r&15)
  const unsigned short* srcA = a_t + (size_t)bx * 32768;
  const unsigned short* srcB = b_t + (size_t)by * 32768;
  #pragma unroll
  for (int it = 0; it < 4; it++) {
    const int idx = it * 1024 + t;       // granule 0..4095
    const int r = idx >> 4, g = idx & 15;
    const int dst = r * 128 + ((g ^ (r & 15)) * 8);
    *(bf16x8*)(&sA[dst]) = *(const bf16x8*)(srcA + idx * 8);
    *(bf16x8*)(&sB[dst]) = *(const bf16x8*)(srcB + idx * 8);
  }
  __syncthreads();

  // GEMM1: K=128 = 4 MFMA k-steps. Wave (wy,wx) owns 64x64.
  const int wy = (w >> 2) * 64, wx = (w & 3) * 64;
  f32x4 acc[4][4];
  #pragma unroll
  for (int a = 0; a < 4; a++)
    #pragma unroll
    for (int c = 0; c < 4; c++) acc[a][c] = (f32x4){0.f, 0.f, 0.f, 0.f};

  #pragma unroll
  for (int ks = 0; ks < 4; ks++) {
    const int g0 = ks * 4 + lq;
    bf16x8 afr[4], bfr[4];
    #pragma unroll
    for (int a = 0; a < 4; a++) {
      const int ra = wy + a * 16 + lr;
      afr[a] = *(const bf16x8*)(&sA[ra * 128 + ((g0 ^ (ra & 15)) * 8)]);
      const int rb = wx + a * 16 + lr;
      bfr[a] = *(const bf16x8*)(&sB[rb * 128 + ((g0 ^ (rb & 15)) * 8)]);
    }
    #pragma unroll
    for (int a = 0; a < 4; a++)
      #pragma unroll
      for (int c = 0; c < 4; c++)
        acc[a][c] = __builtin_amdgcn_mfma_f32_16x16x32_bf16(afr[a], bfr[c], acc[a][c], 0, 0, 0);
  }
  __syncthreads();  // all GEMM1 reads done before sZ overlays sA/sB

  // Transpose: acc (C/D layout) -> sZ[pair][k'=d*32+c], b64 packed-cvt writes.
  // Granule map: gp = (g&~7) | ((g ^ (g>>3) ^ pair) & 7)
  #pragma unroll
  for (int a = 0; a < 4; a++) {
    #pragma unroll
    for (int c = 0; c < 4; c++) {
      const int zrb = wy + a * 16 + lq * 4;
      const int zc  = wx + c * 16 + lr;
      const int pair = (zrb >> 5) * 8 + (zc >> 5);
      const int off = (zc & 31) * 32 + (zrb & 31);
      const int g = off >> 3;
      const int gp = (g & ~7) | ((g ^ (g >> 3) ^ pair) & 7);
      uint2 q;
      q.x = pk2(acc[a][c][0], acc[a][c][1]);
      q.y = pk2(acc[a][c][2], acc[a][c][3]);
      *(uint2*)(&sZ[pair * 1024 + gp * 8 + (off & 7)]) = q;
    }
  }
  __syncthreads();

  // GEMM2: wave = (pg = w&3, og = w>>2). 16 pairs x 32 o x K=1024.
  const int pg = w & 3, og = w >> 2;
  const int p = pg * 16 + lr;
  const unsigned short* wbase0 = wo2 + (size_t)(og * 2) * 16384 + (size_t)l * 8;
  const unsigned short* wbase1 = wbase0 + 16384;
  f32x4 oa[2][2];
  oa[0][0] = oa[0][1] = oa[1][0] = oa[1][1] = (f32x4){0.f, 0.f, 0.f, 0.f};
  #pragma unroll 4
  for (int kk = 0; kk < 32; kk++) {
    const int g = kk * 4 + lq;
    const int gp = (g & ~7) | ((g ^ (g >> 3) ^ p) & 7);
    const bf16x8 zf = *(const bf16x8*)(&sZ[p * 1024 + gp * 8]);
    const bf16x8 w0 = *(const bf16x8*)(wbase0 + kk * 512);
    const bf16x8 w1 = *(const bf16x8*)(wbase1 + kk * 512);
    oa[0][kk & 1] = __builtin_amdgcn_mfma_f32_16x16x32_bf16(zf, w0, oa[0][kk & 1], 0, 0, 0);
    oa[1][kk & 1] = __builtin_amdgcn_mfma_f32_16x16x32_bf16(zf, w1, oa[1][kk & 1], 0, 0, 0);
  }

  // Epilogue: D col = o (lr), row = pair-in-group (lq*4+r)
  #pragma unroll
  for (int f = 0; f < 2; f++) {
    const int o = (og * 2 + f) * 16 + lr;
    const float bov = bo[o];
    #pragma unroll
    for (int r = 0; r < 4; r++) {
      const int pair = pg * 16 + lq * 4 + r;
      const int ii = bx * 8 + (pair >> 3);
      const int jj = by * 8 + (pair & 7);
      const float sc = rnm[ii * N_DIM + jj];
      out[((size_t)(ii * N_DIM + jj)) * COUT + o] =
          (oa[f][0][r] + oa[f][1][r]) * sc + bov;
    }
  }
}

// ---------------------------------------------------------------------------
extern "C" void kernel_launch(void* const* d_in, const int* in_sizes, int n_in,
                              void* d_out, int out_size, void* d_ws, size_t ws_size,
                              hipStream_t stream) {
  const float* m     = (const float*)d_in[0];
  const float* mask  = (const float*)d_in[1];
  const float* gamma = (const float*)d_in[2];
  const float* beta  = (const float*)d_in[3];
  const float* Wa    = (const float*)d_in[4];
  const float* Wb    = (const float*)d_in[5];
  const float* Wo    = (const float*)d_in[6];
  const float* bo    = (const float*)d_in[7];
  float* out = (float*)d_out;

  char* ws = (char*)d_ws;
  float*          rnm = (float*)(ws);                     // 256 KB
  unsigned short* wo2 = (unsigned short*)(ws + 262144);   // 256 KB
  unsigned short* a_t = (unsigned short*)(ws + 524288);   //   2 MB
  unsigned short* b_t = (unsigned short*)(ws + 2621440);  //   2 MB

  hipFuncSetAttribute((const void*)fused_kernel,
                      hipFuncAttributeMaxDynamicSharedMemorySize, 131072);

  lnp_prep_kernel<<<1408, 256, 0, stream>>>(m, mask, gamma, beta, Wa, Wb, Wo,
                                            rnm, wo2, a_t, b_t);
  fused_kernel<<<dim3(32, 32), 1024, 131072, stream>>>(a_t, b_t, wo2, rnm, bo, out);
}

// Round 8
// 146.563 us; speedup vs baseline: 1.4267x; 1.0727x over previous
//
#include <hip/hip_runtime.h>
#include <hip/hip_bf16.h>

#define S_DIM 128
#define N_DIM 256
#define CIN   256
#define CH    32
#define COUT  128

typedef __attribute__((ext_vector_type(8))) short bf16x8;
typedef __attribute__((ext_vector_type(4))) float f32x4;
typedef __attribute__((ext_vector_type(16))) float f32x16;

__device__ __forceinline__ unsigned short f2bf(float f) {
  union { float f; unsigned int u; } v; v.f = f;
  unsigned int u = v.u;
  return (unsigned short)((u + 0x7FFFu + ((u >> 16) & 1u)) >> 16);
}

// packed f32x2 -> bf16x2 (RNE)
__device__ __forceinline__ unsigned int pk2(float x, float y) {
  float2 f2; f2.x = x; f2.y = y;
  __hip_bfloat162 h = __float22bfloat162_rn(f2);
  union { __hip_bfloat162 h; unsigned int u; } c; c.h = h;
  return c.u;
}

// ---------------------------------------------------------------------------
// Front-end (R4-verified): merged LN+projection and prep.
//   blocks 0..1023   : LayerNorm + MFMA projection (wab in LDS)
//   blocks 1024..1151: wo3 = Wo bf16 packed for 32x32x16 B-frags:
//                      wo3[((og*64+step)*64 + lane)*8 + e] =
//                        Wo[o = og*32+(lane&31)][c*32+d],
//                        k' = step*16 + (lane>>5)*8 + e, c=k'&31, d=k'>>5
//   blocks 1152..1407: rnm = 1 / clip(mask^T mask, 1)
// ---------------------------------------------------------------------------
__global__ __launch_bounds__(256) void lnp_prep_kernel(
    const float* __restrict__ m, const float* __restrict__ mask,
    const float* __restrict__ gamma, const float* __restrict__ beta,
    const float* __restrict__ Wa, const float* __restrict__ Wb,
    const float* __restrict__ Wo,
    float* __restrict__ rnm, unsigned short* __restrict__ wo3,
    unsigned short* __restrict__ a_t, unsigned short* __restrict__ b_t) {
  const int b = blockIdx.x, t = threadIdx.x;
  if (b < 1024) {
    __shared__ __align__(16) unsigned short mn[32][264];   // +8 pad
    __shared__ __align__(16) unsigned short wabs[64 * 256];
    const int i = b & 255, s0 = (b >> 8) * 32;
    const int w = t >> 6, l = t & 63, lq = l >> 4, lr = l & 15;

    // Wa/Wb -> wabs, granule-swizzled: g' = (g&16)|((g ^ (r&15))&15)
    #pragma unroll
    for (int it = 0; it < 8; it++) {
      const int gi = it * 256 + t;       // granule 0..2047 (64 rows x 32)
      const int r = gi >> 5, g = gi & 31;
      const float* src = (r < 32) ? (Wa + r * 256 + g * 8)
                                  : (Wb + (r - 32) * 256 + g * 8);
      const int gp = (g & 16) | ((g ^ (r & 15)) & 15);
      unsigned short* dst = &wabs[r * 256 + gp * 8];
      const float4 v0 = *(const float4*)(src);
      const float4 v1 = *(const float4*)(src + 4);
      dst[0] = f2bf(v0.x); dst[1] = f2bf(v0.y); dst[2] = f2bf(v0.z); dst[3] = f2bf(v0.w);
      dst[4] = f2bf(v1.x); dst[5] = f2bf(v1.y); dst[6] = f2bf(v1.z); dst[7] = f2bf(v1.w);
    }

    const float4 g4 = *(const float4*)(gamma + l * 4);
    const float4 b4 = *(const float4*)(beta + l * 4);

    for (int rr = 0; rr < 8; rr++) {
      const int r = w * 8 + rr;
      const int s = s0 + r;
      const float4 v = *(const float4*)(m + ((size_t)(s * N_DIM + i)) * CIN + l * 4);
      float sum = v.x + v.y + v.z + v.w;
      float sq  = v.x * v.x + v.y * v.y + v.z * v.z + v.w * v.w;
      #pragma unroll
      for (int off = 32; off > 0; off >>= 1) {
        sum += __shfl_down(sum, off);
        sq  += __shfl_down(sq, off);
      }
      sum = __shfl(sum, 0); sq = __shfl(sq, 0);
      const float mu = sum * (1.0f / CIN);
      const float var = fmaxf(sq * (1.0f / CIN) - mu * mu, 0.0f);
      const float rs = rsqrtf(var + 1e-5f);
      const float mk = mask[s * N_DIM + i];
      ushort4 p;
      p.x = f2bf(((v.x - mu) * rs * g4.x + b4.x) * mk);
      p.y = f2bf(((v.y - mu) * rs * g4.y + b4.y) * mk);
      p.z = f2bf(((v.z - mu) * rs * g4.z + b4.z) * mk);
      p.w = f2bf(((v.w - mu) * rs * g4.w + b4.w) * mk);
      *(ushort4*)(&mn[r][l * 4]) = p;
    }
    __syncthreads();

    // MFMA: M=32 s-rows, N=64 [Wa|Wb], K=256
    const int wm = w & 1;
    const int n2 = w >> 1;
    f32x4 acc0 = {0.f, 0.f, 0.f, 0.f}, acc1 = {0.f, 0.f, 0.f, 0.f};
    #pragma unroll
    for (int ks = 0; ks < 8; ks++) {
      const int k0 = ks * 32 + lq * 8;
      const int g = ks * 4 + lq;
      const int gp = (g & 16) | ((g ^ lr) & 15);
      const bf16x8 af = *(const bf16x8*)(&mn[wm * 16 + lr][k0]);
      const bf16x8 bf0 = *(const bf16x8*)(&wabs[(n2 * 32 + lr) * 256 + gp * 8]);
      const bf16x8 bf1 = *(const bf16x8*)(&wabs[(n2 * 32 + 16 + lr) * 256 + gp * 8]);
      acc0 = __builtin_amdgcn_mfma_f32_16x16x32_bf16(af, bf0, acc0, 0, 0, 0);
      acc1 = __builtin_amdgcn_mfma_f32_16x16x32_bf16(af, bf1, acc1, 0, 0, 0);
    }

    unsigned short* dst = (n2 == 0) ? a_t : b_t;
    const int scol = s0 + wm * 16 + lq * 4;
    ushort4 q0, q1;
    q0.x = f2bf(acc0[0]); q0.y = f2bf(acc0[1]); q0.z = f2bf(acc0[2]); q0.w = f2bf(acc0[3]);
    q1.x = f2bf(acc1[0]); q1.y = f2bf(acc1[1]); q1.z = f2bf(acc1[2]); q1.w = f2bf(acc1[3]);
    *(ushort4*)(dst + ((size_t)(i * CH + lr)) * S_DIM + scol) = q0;
    *(ushort4*)(dst + ((size_t)(i * CH + 16 + lr)) * S_DIM + scol) = q1;
  } else if (b < 1152) {
    const int r = b - 1024;  // 0..127
    #pragma unroll
    for (int q = 0; q < 4; q++) {
      const int f = r * 1024 + q * 256 + t;        // 0..131071
      const int e = f & 7, l = (f >> 3) & 63;
      const int step = (f >> 9) & 63, og = f >> 15;
      const int kp = step * 16 + (l >> 5) * 8 + e;
      const int c = kp & 31, d = kp >> 5;
      const int o = og * 32 + (l & 31);
      wo3[f] = f2bf(Wo[o * 1024 + c * 32 + d]);
    }
  } else {
    const int i = b - 1152;  // 0..255
    float acc = 0.f;
    #pragma unroll 8
    for (int s = 0; s < S_DIM; s++)
      acc += mask[s * N_DIM + i] * mask[s * N_DIM + t];
    acc = fmaxf(acc, 1.0f);
    rnm[i * N_DIM + t] = 1.0f / acc;
  }
}

// ---------------------------------------------------------------------------
// fused v5: staged GEMM1 (16x16x32, verified) + GEMM2 via 32x32x16 with
// 2-way K-split. 256x256 z-tile (64 pairs), 16 waves, 128 KB dynamic LDS.
//   stage  : sA/sB 64 KB each, XOR-swizzled 16B granules
//   GEMM1  : wave grid 4x4, 64x64 per wave, K=128
//   transp : C/D accs -> sZ[pair][k'=d*32+c] (b64 packed-cvt writes)
//   GEMM2  : wave = (ph = w&1: 32 pairs, og = (w>>1)&3: 32 o, kh = w>>3:
//            K half). 32x32x16 MFMA: 1 z-read + 1 wo-read + 1 MFMA per step.
//            z-LDS reads 512/block (was 1024), wo-L2 512 KB (L1-shared by ph).
//   reduce : kh=1 partials through freed sZ (32 KB), kh=0 adds + epilogue.
// ---------------------------------------------------------------------------
__global__ __launch_bounds__(1024, 4) void fused_kernel(
    const unsigned short* __restrict__ a_t, const unsigned short* __restrict__ b_t,
    const unsigned short* __restrict__ wo3, const float* __restrict__ rnm,
    const float* __restrict__ bo, float* __restrict__ out) {
  extern __shared__ __align__(16) unsigned short smem[];
  unsigned short* sA = smem;            // 256 x 128 = 64 KB
  unsigned short* sB = smem + 32768;    // 256 x 128 = 64 KB
  unsigned short* sZ = smem;            // 64 pairs x 1024 = 128 KB overlay

  const int t = threadIdx.x, w = t >> 6, l = t & 63;
  const int lq = l >> 4, lr = l & 15;
  const int bx = blockIdx.x, by = blockIdx.y;

  // Stage: 4096 granules/tile; swizzle g' = g ^ (r&15)
  const unsigned short* srcA = a_t + (size_t)bx * 32768;
  const unsigned short* srcB = b_t + (size_t)by * 32768;
  #pragma unroll
  for (int it = 0; it < 4; it++) {
    const int idx = it * 1024 + t;       // granule 0..4095
    const int r = idx >> 4, g = idx & 15;
    const int dst = r * 128 + ((g ^ (r & 15)) * 8);
    *(bf16x8*)(&sA[dst]) = *(const bf16x8*)(srcA + idx * 8);
    *(bf16x8*)(&sB[dst]) = *(const bf16x8*)(srcB + idx * 8);
  }
  __syncthreads();

  // GEMM1: K=128 = 4 MFMA k-steps. Wave (wy,wx) owns 64x64.
  const int wy = (w >> 2) * 64, wx = (w & 3) * 64;
  f32x4 acc[4][4];
  #pragma unroll
  for (int a = 0; a < 4; a++)
    #pragma unroll
    for (int c = 0; c < 4; c++) acc[a][c] = (f32x4){0.f, 0.f, 0.f, 0.f};

  #pragma unroll
  for (int ks = 0; ks < 4; ks++) {
    const int g0 = ks * 4 + lq;
    bf16x8 afr[4], bfr[4];
    #pragma unroll
    for (int a = 0; a < 4; a++) {
      const int ra = wy + a * 16 + lr;
      afr[a] = *(const bf16x8*)(&sA[ra * 128 + ((g0 ^ (ra & 15)) * 8)]);
      const int rb = wx + a * 16 + lr;
      bfr[a] = *(const bf16x8*)(&sB[rb * 128 + ((g0 ^ (rb & 15)) * 8)]);
    }
    #pragma unroll
    for (int a = 0; a < 4; a++)
      #pragma unroll
      for (int c = 0; c < 4; c++)
        acc[a][c] = __builtin_amdgcn_mfma_f32_16x16x32_bf16(afr[a], bfr[c], acc[a][c], 0, 0, 0);
  }
  __syncthreads();  // all GEMM1 reads done before sZ overlays sA/sB

  // Transpose: acc (C/D layout) -> sZ[pair][k'=d*32+c], b64 packed-cvt writes.
  // Granule map: gp = (g&~7) | ((g ^ (g>>3) ^ pair) & 7)
  #pragma unroll
  for (int a = 0; a < 4; a++) {
    #pragma unroll
    for (int c = 0; c < 4; c++) {
      const int zrb = wy + a * 16 + lq * 4;
      const int zc  = wx + c * 16 + lr;
      const int pair = (zrb >> 5) * 8 + (zc >> 5);
      const int off = (zc & 31) * 32 + (zrb & 31);
      const int g = off >> 3;
      const int gp = (g & ~7) | ((g ^ (g >> 3) ^ pair) & 7);
      uint2 q;
      q.x = pk2(acc[a][c][0], acc[a][c][1]);
      q.y = pk2(acc[a][c][2], acc[a][c][3]);
      *(uint2*)(&sZ[pair * 1024 + gp * 8 + (off & 7)]) = q;
    }
  }
  __syncthreads();

  // GEMM2: 32x32x16. A-frag: m = pair = ph*32+(l&31), k = (l>>5)*8+j.
  // B-frag: n = o = og*32+(l&31), same k chunks (wo3 pre-packed).
  const int ph = w & 1, og = (w >> 1) & 3, kh = w >> 3;
  const int pair2 = ph * 32 + (l & 31);
  const int zbase = pair2 * 1024;
  const unsigned short* wop =
      wo3 + ((size_t)(og * 64 + kh * 32) * 64 + l) * 8;
  f32x16 acc2;
  #pragma unroll
  for (int r = 0; r < 16; r++) acc2[r] = 0.f;

  #pragma unroll 8
  for (int j = 0; j < 32; j++) {
    const int s = kh * 32 + j;                 // k-step (16 k each)
    const int g = s * 2 + (l >> 5);            // granule of this lane's chunk
    const int gp = (g & ~7) | ((g ^ (g >> 3) ^ pair2) & 7);
    const bf16x8 zf = *(const bf16x8*)(&sZ[zbase + gp * 8]);
    const bf16x8 wf = *(const bf16x8*)(wop + j * 512);
    acc2 = __builtin_amdgcn_mfma_f32_32x32x16_bf16(zf, wf, acc2, 0, 0, 0);
  }
  __syncthreads();   // all z reads done; sZ region now free for reduction

  // Cross-kh reduction through LDS (b32 lane-consecutive: 2-way, free)
  float* fpart = (float*)sZ;                   // 128 rows x 64 = 32 KB
  const int job = w & 7;
  if (kh) {
    #pragma unroll
    for (int r = 0; r < 16; r++)
      fpart[(job * 16 + r) * 64 + l] = acc2[r];
  }
  __syncthreads();

  if (!kh) {
    // D layout (32x32): col = o = og*32+(l&31); row = (r&3)+8*(r>>2)+4*(l>>5)
    const int o = og * 32 + (l & 31);
    const float bov = bo[o];
    #pragma unroll
    for (int r = 0; r < 16; r++) {
      const int row = (r & 3) + 8 * (r >> 2) + 4 * (l >> 5);
      const int pr = ph * 32 + row;            // pair = i_loc*8 + j_loc
      const int ii = bx * 8 + (pr >> 3);
      const int jj = by * 8 + (pr & 7);
      const float sc = rnm[ii * N_DIM + jj];
      out[((size_t)(ii * N_DIM + jj)) * COUT + o] =
          (acc2[r] + fpart[(job * 16 + r) * 64 + l]) * sc + bov;
    }
  }
}

// ---------------------------------------------------------------------------
extern "C" void kernel_launch(void* const* d_in, const int* in_sizes, int n_in,
                              void* d_out, int out_size, void* d_ws, size_t ws_size,
                              hipStream_t stream) {
  const float* m     = (const float*)d_in[0];
  const float* mask  = (const float*)d_in[1];
  const float* gamma = (const float*)d_in[2];
  const float* beta  = (const float*)d_in[3];
  const float* Wa    = (const float*)d_in[4];
  const float* Wb    = (const float*)d_in[5];
  const float* Wo    = (const float*)d_in[6];
  const float* bo    = (const float*)d_in[7];
  float* out = (float*)d_out;

  char* ws = (char*)d_ws;
  float*          rnm = (float*)(ws);                     // 256 KB
  unsigned short* wo3 = (unsigned short*)(ws + 262144);   // 256 KB
  unsigned short* a_t = (unsigned short*)(ws + 524288);   //   2 MB
  unsigned short* b_t = (unsigned short*)(ws + 2621440);  //   2 MB

  hipFuncSetAttribute((const void*)fused_kernel,
                      hipFuncAttributeMaxDynamicSharedMemorySize, 131072);

  lnp_prep_kernel<<<1408, 256, 0, stream>>>(m, mask, gamma, beta, Wa, Wb, Wo,
                                            rnm, wo3, a_t, b_t);
  fused_kernel<<<dim3(32, 32), 1024, 131072, stream>>>(a_t, b_t, wo3, rnm, bo, out);
}